// Round 14
// baseline (165.108 us; speedup 1.0000x reference)
//
#include <hip/hip_runtime.h>

#define N_ROWS 8192
#define D_IN 1024
#define D_OUT 4096
#define NGROUPS 8
#define NT_K 16       // K tiles of 64
#define MAX_MT 72     // max 128-row m-tiles incl. per-group padding
#define NCONV 4096    // convA blocks in fused prep

typedef unsigned short ushort_t;
typedef __attribute__((ext_vector_type(8))) __bf16 bf16x8;
typedef __attribute__((ext_vector_type(4))) float f32x4;
typedef __attribute__((ext_vector_type(8))) unsigned short us8;

// ctl int-index layout in ws:
//  [28] num_tiles  [32..319] tiles (int4: g,start,rows,pad) up to 72
//  [512..] sorted row ids (8192)
#define CTL_NT 28
#define CTL_TILES 32
#define CTL_SORTED 512

__device__ __forceinline__ unsigned short f2bf(float f) {
  union { float f; unsigned u; } v; v.f = f;
  unsigned r = v.u + 0x7FFFu + ((v.u >> 16) & 1u);
  return (unsigned short)(r >> 16);
}

__device__ __forceinline__ void gload_lds16(const void* g, void* l) {
  __builtin_amdgcn_global_load_lds(
      (const __attribute__((address_space(1))) void*)g,
      (__attribute__((address_space(3))) void*)l, 16, 0, 0);
}

// Fused prep: block 0 = stable counting sort + tile build; blocks 1..NCONV =
// A f32->bf16; rest = W transpose+convert (XOR-swizzle baked).
__global__ __launch_bounds__(256) void k_prep(
    const float* __restrict__ A, const int* __restrict__ gi,
    const float* __restrict__ W, ushort_t* __restrict__ Ab,
    ushort_t* __restrict__ Wt, int* __restrict__ ctl,
    int* __restrict__ sorted) {
  __shared__ int hist[NGROUPS][256];
  __shared__ int base[NGROUPS];
  __shared__ float tile[64][66];
  const int bid = blockIdx.x;
  const int t = threadIdx.x;

  if (bid == 0) {
    // ---- stable counting sort (ascending ids per group), 32 items/thread
    int loc[NGROUPS];
#pragma unroll
    for (int gg = 0; gg < NGROUPS; ++gg) loc[gg] = 0;
    for (int i = 0; i < 32; ++i) ++loc[gi[t * 32 + i]];
#pragma unroll
    for (int gg = 0; gg < NGROUPS; ++gg) hist[gg][t] = loc[gg];
    __syncthreads();
    for (int d = 1; d < 256; d <<= 1) {
      int v[NGROUPS];
#pragma unroll
      for (int gg = 0; gg < NGROUPS; ++gg)
        v[gg] = (t >= d) ? hist[gg][t - d] : 0;
      __syncthreads();
#pragma unroll
      for (int gg = 0; gg < NGROUPS; ++gg) hist[gg][t] += v[gg];
      __syncthreads();
    }
    if (t == 0) {
      int off = 0, T = 0;
      int* tiles = ctl + CTL_TILES;
      for (int gg = 0; gg < NGROUPS; ++gg) {
        base[gg] = off;
        int c = hist[gg][255];
        for (int m0 = 0; m0 < c; m0 += 128) {
          tiles[T * 4 + 0] = gg;
          tiles[T * 4 + 1] = off + m0;
          tiles[T * 4 + 2] = min(128, c - m0);
          tiles[T * 4 + 3] = 0;
          ++T;
        }
        off += c;
      }
      ctl[CTL_NT] = T;
    }
    __syncthreads();
    int pos[NGROUPS];
#pragma unroll
    for (int gg = 0; gg < NGROUPS; ++gg)
      pos[gg] = base[gg] + hist[gg][t] - loc[gg];  // exclusive prefix
    for (int i = 0; i < 32; ++i) {
      int g2 = gi[t * 32 + i];
      sorted[pos[g2]++] = t * 32 + i;
    }
  } else if (bid <= NCONV) {
    // ---- convA: 8 elems/thread
    size_t i = ((size_t)(bid - 1) * 256 + t) * 8;
    float4 v0 = *reinterpret_cast<const float4*>(A + i);
    float4 v1 = *reinterpret_cast<const float4*>(A + i + 4);
    us8 o;
    o[0] = f2bf(v0.x); o[1] = f2bf(v0.y); o[2] = f2bf(v0.z); o[3] = f2bf(v0.w);
    o[4] = f2bf(v1.x); o[5] = f2bf(v1.y); o[6] = f2bf(v1.z); o[7] = f2bf(v1.w);
    *reinterpret_cast<us8*>(Ab + i) = o;
  } else {
    // ---- transW: W [g][k][n] f32 -> Wt [g][kt16][n4096][k64] bf16,
    // chunk c of row n stored at slot (c ^ (n&7)).
    int idx = bid - 1 - NCONV;          // 0..8191
    int g = idx >> 10;
    int rem = idx & 1023;
    int kt = rem >> 6;
    int n0 = (rem & 63) * 64;
    int k0 = kt * 64;
    int ln = (t & 15) * 4;
    int lk = t >> 4;
#pragma unroll
    for (int i = 0; i < 4; ++i) {
      int k = i * 16 + lk;
      float4 v = *reinterpret_cast<const float4*>(
          &W[((size_t)g * D_IN + k0 + k) * D_OUT + n0 + ln]);
      tile[k][ln] = v.x; tile[k][ln + 1] = v.y;
      tile[k][ln + 2] = v.z; tile[k][ln + 3] = v.w;
    }
    __syncthreads();
    int n = t & 63;
    int c0 = t >> 6;
#pragma unroll
    for (int i = 0; i < 2; ++i) {
      int c = c0 + i * 4;
      us8 u;
#pragma unroll
      for (int q = 0; q < 8; ++q) u[q] = f2bf(tile[c * 8 + q][n]);
      int slot = c ^ (n & 7);
      *reinterpret_cast<us8*>(
          &Wt[((size_t)(g * 16 + kt) * D_OUT + n0 + n) * 64 + slot * 8]) = u;
    }
  }
}

// ---- m97-structure grouped GEMM (R9 base): 128x128 tile, BK=64, 4 waves,
// single-buffered LDS (32.5 KB), plain 2-syncthreads K-loop, 3 blocks/CU,
// mfma_f32_16x16x32_bf16, NATURAL dispatch order.
// NEW: per-block K-phase stagger — co-resident blocks start the K-loop at
// different tiles (kt0 = (bx + 3*tI) & 15) so their stage->drain->compute
// phases decorrelate and one block's MFMA covers another's barrier drain.
// Same addresses/work; only fp accumulation order changes (headroom 3.7x).
// LDS [row128][k64] bf16, 128B rows, XOR-swizzled 16B chunks (baked in Wt /
// pre-swizzled A source), conflict-free ds_read_b128.

__global__ __launch_bounds__(256, 3) void k_gemm(
    const ushort_t* __restrict__ Ab, const ushort_t* __restrict__ Wt,
    const int* __restrict__ ctl, const int* __restrict__ sorted,
    const float* __restrict__ bias, float* __restrict__ out) {
  const int tI = blockIdx.y;
  const int bx = blockIdx.x;
  if (tI >= ctl[CTL_NT]) return;
  const int4 tl = reinterpret_cast<const int4*>(ctl + CTL_TILES)[tI];
  const int g = tl.x, start = tl.y, rows = tl.z;
  const int n_base = bx * 128;
  const int kt0 = (bx + 3 * tI) & 15;   // K-phase stagger

  __shared__ ushort_t Asm[128 * 64];  // 16 KB, [row128][k64] 128B rows
  __shared__ ushort_t Bsm[128 * 64];  // 16 KB
  __shared__ int rowid[128];

  const int t = threadIdx.x;
  const int lane = t & 63;
  const int w = t >> 6;
  if (t < 128) rowid[t] = sorted[start + ((t < rows) ? t : 0)];
  __syncthreads();

  // staging: call j covers LDS rows I*8..I*8+7 (I = j*4+w), 128B/row.
  // lane -> (row I*8+lr, chunk lc); A source pre-swizzled chunk lc^lr.
  const int lr = lane >> 3, lc = lane & 7;
  const int schunk = lc ^ lr;
  size_t aSrc[4];
  const ushort_t* bSrc[4];
  int ldOff[4];
  const ushort_t* bRegion = Wt + ((size_t)g * 16 * D_OUT + n_base) * 64;
#pragma unroll
  for (int j = 0; j < 4; ++j) {
    int I = j * 4 + w;
    aSrc[j] = (size_t)rowid[I * 8 + lr] * D_IN + schunk * 8;
    bSrc[j] = bRegion + I * 512 + lane * 8;
    ldOff[j] = I * 1024;  // bytes
  }

  const int fr = lane & 15;
  const int fk = lane >> 4;
  const int fk16 = fk * 16;
  const int xr = (fr & 7) << 4;
  const int wm = (w >> 1) * 64;
  const int wn = (w & 1) * 64;
  const char* aCh = (const char*)Asm + (wm + fr) * 128;
  const char* bCh = (const char*)Bsm + (wn + fr) * 128;

  f32x4 acc[4][4];
#pragma unroll
  for (int a = 0; a < 4; ++a)
#pragma unroll
    for (int b = 0; b < 4; ++b) acc[a][b] = (f32x4){0.f, 0.f, 0.f, 0.f};

  bf16x8 Af[2][4], Bf[2][4];

  for (int i = 0; i < NT_K; ++i) {
    const int kt = (kt0 + i) & 15;
    // stage tile kt (single buffer)
#pragma unroll
    for (int j = 0; j < 4; ++j)
      gload_lds16(Ab + aSrc[j] + (size_t)kt * 64, (char*)Asm + ldOff[j]);
#pragma unroll
    for (int j = 0; j < 4; ++j)
      gload_lds16(bSrc[j] + (size_t)kt * 262144, (char*)Bsm + ldOff[j]);
    __syncthreads();  // drains vmcnt; loads landed

#pragma unroll
    for (int ks = 0; ks < 2; ++ks) {
#pragma unroll
      for (int jm = 0; jm < 4; ++jm)
        Af[ks][jm] = *reinterpret_cast<const bf16x8*>(
            aCh + (jm * 16) * 128 + ((ks * 64 + fk16) ^ xr));
#pragma unroll
      for (int jn = 0; jn < 4; ++jn)
        Bf[ks][jn] = *reinterpret_cast<const bf16x8*>(
            bCh + (jn * 16) * 128 + ((ks * 64 + fk16) ^ xr));
    }
#pragma unroll
    for (int ks = 0; ks < 2; ++ks)
#pragma unroll
      for (int jm = 0; jm < 4; ++jm)
#pragma unroll
        for (int jn = 0; jn < 4; ++jn)
          acc[jm][jn] = __builtin_amdgcn_mfma_f32_16x16x32_bf16(
              Af[ks][jm], Bf[ks][jn], acc[jm][jn], 0, 0, 0);
    __syncthreads();  // reads done before next tile's writes
  }

  // epilogue: bias + masked scattered row stores
  const float* bp = bias + g * D_OUT + n_base + wn;
  float bv[4];
#pragma unroll
  for (int nb = 0; nb < 4; ++nb) bv[nb] = bp[nb * 16 + fr];
#pragma unroll
  for (int mb = 0; mb < 4; ++mb) {
#pragma unroll
    for (int r = 0; r < 4; ++r) {
      int m = wm + mb * 16 + fk * 4 + r;
      if (m < rows) {
        size_t ro = (size_t)rowid[m] * D_OUT + n_base + wn;
#pragma unroll
        for (int nb = 0; nb < 4; ++nb)
          out[ro + nb * 16 + fr] = acc[mb][nb][r] + bv[nb];
      }
    }
  }
}

// Fallback if workspace is too small: naive fp32 (correct, slow).
__global__ void k_naive(const float* __restrict__ A, const int* __restrict__ gi,
                        const float* __restrict__ W, const float* __restrict__ B,
                        float* __restrict__ out) {
  int row = blockIdx.x;
  int n = blockIdx.y * 256 + threadIdx.x;
  int g = gi[row];
  float s = B[(size_t)g * D_OUT + n];
  const float* wp = W + (size_t)g * D_IN * D_OUT + n;
  const float* a = A + (size_t)row * D_IN;
  for (int k = 0; k < D_IN; ++k) s += a[k] * wp[(size_t)k * D_OUT];
  out[(size_t)row * D_OUT + n] = s;
}

extern "C" void kernel_launch(void* const* d_in, const int* in_sizes, int n_in,
                              void* d_out, int out_size, void* d_ws, size_t ws_size,
                              hipStream_t stream) {
  const float* A = (const float*)d_in[0];
  const int* gi = (const int*)d_in[1];
  const float* W = (const float*)d_in[2];
  const float* B = (const float*)d_in[3];
  float* out = (float*)d_out;

  const size_t A_OFF = 65536;
  const size_t W_OFF = A_OFF + (size_t)N_ROWS * D_IN * 2;
  const size_t NEED = W_OFF + (size_t)NGROUPS * D_IN * D_OUT * 2;

  if (ws_size < NEED) {
    dim3 grid(N_ROWS, D_OUT / 256);
    k_naive<<<grid, dim3(256), 0, stream>>>(A, gi, W, B, out);
    return;
  }

  int* ctl = (int*)d_ws;
  int* sorted = ctl + CTL_SORTED;
  ushort_t* Ab = (ushort_t*)((char*)d_ws + A_OFF);
  ushort_t* Wt = (ushort_t*)((char*)d_ws + W_OFF);

  // fused prep: 1 sort block + 4096 convA blocks + 8192 transW blocks
  k_prep<<<1 + NCONV + 8192, 256, 0, stream>>>(A, gi, W, Ab, Wt, ctl, sorted);
  dim3 gg(32, MAX_MT);
  k_gemm<<<gg, 256, 0, stream>>>(Ab, Wt, ctl, sorted, B, out);
}

// Round 15
// 133.391 us; speedup vs baseline: 1.2378x; 1.2378x over previous
//
#include <hip/hip_runtime.h>

#define N_ROWS 8192
#define D_IN 1024
#define D_OUT 4096
#define NGROUPS 8
#define NT_K 16       // K tiles of 64
#define MAX_MT 72     // max 128-row m-tiles incl. per-group padding
#define NCONV 4096    // convA blocks in fused prep

typedef unsigned short ushort_t;
typedef __attribute__((ext_vector_type(8))) __bf16 bf16x8;
typedef __attribute__((ext_vector_type(4))) float f32x4;
typedef __attribute__((ext_vector_type(8))) unsigned short us8;

// ctl int-index layout in ws:
//  [28] num_tiles  [32..319] tiles (int4: g,start,rows,pad) up to 72
//  [512..] sorted row ids (8192)
#define CTL_NT 28
#define CTL_TILES 32
#define CTL_SORTED 512

__device__ __forceinline__ unsigned short f2bf(float f) {
  union { float f; unsigned u; } v; v.f = f;
  unsigned r = v.u + 0x7FFFu + ((v.u >> 16) & 1u);
  return (unsigned short)(r >> 16);
}

__device__ __forceinline__ void gload_lds16(const void* g, void* l) {
  __builtin_amdgcn_global_load_lds(
      (const __attribute__((address_space(1))) void*)g,
      (__attribute__((address_space(3))) void*)l, 16, 0, 0);
}

// Fused prep: block 0 = stable counting sort + tile build; blocks 1..NCONV =
// A f32->bf16; rest = W transpose+convert (XOR-swizzle baked).
__global__ __launch_bounds__(256) void k_prep(
    const float* __restrict__ A, const int* __restrict__ gi,
    const float* __restrict__ W, ushort_t* __restrict__ Ab,
    ushort_t* __restrict__ Wt, int* __restrict__ ctl,
    int* __restrict__ sorted) {
  __shared__ int hist[NGROUPS][256];
  __shared__ int base[NGROUPS];
  __shared__ float tile[64][66];
  const int bid = blockIdx.x;
  const int t = threadIdx.x;

  if (bid == 0) {
    // ---- stable counting sort (ascending ids per group), 32 items/thread
    int loc[NGROUPS];
#pragma unroll
    for (int gg = 0; gg < NGROUPS; ++gg) loc[gg] = 0;
    for (int i = 0; i < 32; ++i) ++loc[gi[t * 32 + i]];
#pragma unroll
    for (int gg = 0; gg < NGROUPS; ++gg) hist[gg][t] = loc[gg];
    __syncthreads();
    for (int d = 1; d < 256; d <<= 1) {
      int v[NGROUPS];
#pragma unroll
      for (int gg = 0; gg < NGROUPS; ++gg)
        v[gg] = (t >= d) ? hist[gg][t - d] : 0;
      __syncthreads();
#pragma unroll
      for (int gg = 0; gg < NGROUPS; ++gg) hist[gg][t] += v[gg];
      __syncthreads();
    }
    if (t == 0) {
      int off = 0, T = 0;
      int* tiles = ctl + CTL_TILES;
      for (int gg = 0; gg < NGROUPS; ++gg) {
        base[gg] = off;
        int c = hist[gg][255];
        for (int m0 = 0; m0 < c; m0 += 128) {
          tiles[T * 4 + 0] = gg;
          tiles[T * 4 + 1] = off + m0;
          tiles[T * 4 + 2] = min(128, c - m0);
          tiles[T * 4 + 3] = 0;
          ++T;
        }
        off += c;
      }
      ctl[CTL_NT] = T;
    }
    __syncthreads();
    int pos[NGROUPS];
#pragma unroll
    for (int gg = 0; gg < NGROUPS; ++gg)
      pos[gg] = base[gg] + hist[gg][t] - loc[gg];  // exclusive prefix
    for (int i = 0; i < 32; ++i) {
      int g2 = gi[t * 32 + i];
      sorted[pos[g2]++] = t * 32 + i;
    }
  } else if (bid <= NCONV) {
    // ---- convA: 8 elems/thread
    size_t i = ((size_t)(bid - 1) * 256 + t) * 8;
    float4 v0 = *reinterpret_cast<const float4*>(A + i);
    float4 v1 = *reinterpret_cast<const float4*>(A + i + 4);
    us8 o;
    o[0] = f2bf(v0.x); o[1] = f2bf(v0.y); o[2] = f2bf(v0.z); o[3] = f2bf(v0.w);
    o[4] = f2bf(v1.x); o[5] = f2bf(v1.y); o[6] = f2bf(v1.z); o[7] = f2bf(v1.w);
    *reinterpret_cast<us8*>(Ab + i) = o;
  } else {
    // ---- transW: W [g][k][n] f32 -> Wt [g][kt16][n4096][k64] bf16,
    // chunk c of row n stored at slot (c ^ (n&7)).
    int idx = bid - 1 - NCONV;          // 0..8191
    int g = idx >> 10;
    int rem = idx & 1023;
    int kt = rem >> 6;
    int n0 = (rem & 63) * 64;
    int k0 = kt * 64;
    int ln = (t & 15) * 4;
    int lk = t >> 4;
#pragma unroll
    for (int i = 0; i < 4; ++i) {
      int k = i * 16 + lk;
      float4 v = *reinterpret_cast<const float4*>(
          &W[((size_t)g * D_IN + k0 + k) * D_OUT + n0 + ln]);
      tile[k][ln] = v.x; tile[k][ln + 1] = v.y;
      tile[k][ln + 2] = v.z; tile[k][ln + 3] = v.w;
    }
    __syncthreads();
    int n = t & 63;
    int c0 = t >> 6;
#pragma unroll
    for (int i = 0; i < 2; ++i) {
      int c = c0 + i * 4;
      us8 u;
#pragma unroll
      for (int q = 0; q < 8; ++q) u[q] = f2bf(tile[c * 8 + q][n]);
      int slot = c ^ (n & 7);
      *reinterpret_cast<us8*>(
          &Wt[((size_t)(g * 16 + kt) * D_OUT + n0 + n) * 64 + slot * 8]) = u;
    }
  }
}

// ---- m97-structure grouped GEMM (measured best, R9/R13): 128x128 tile,
// BK=64, 4 waves (each 64x64), single-buffered LDS (32.5 KB), plain
// 2-syncthreads K-loop, 3 blocks/CU (implicit cross-block overlap, m114),
// mfma_f32_16x16x32_bf16. NATURAL dispatch order, SYNCHRONIZED K-phase:
// co-resident blocks read the same B k-panel simultaneously -> live working
// set stays small and L3-hot (R14: staggering it tripled FETCH, -15%).
// LDS [row128][k64] bf16, 128B rows, XOR-swizzled 16B chunks (baked in Wt /
// pre-swizzled A source), conflict-free ds_read_b128.

__global__ __launch_bounds__(256, 3) void k_gemm(
    const ushort_t* __restrict__ Ab, const ushort_t* __restrict__ Wt,
    const int* __restrict__ ctl, const int* __restrict__ sorted,
    const float* __restrict__ bias, float* __restrict__ out) {
  const int tI = blockIdx.y;
  const int bx = blockIdx.x;
  if (tI >= ctl[CTL_NT]) return;
  const int4 tl = reinterpret_cast<const int4*>(ctl + CTL_TILES)[tI];
  const int g = tl.x, start = tl.y, rows = tl.z;
  const int n_base = bx * 128;

  __shared__ ushort_t Asm[128 * 64];  // 16 KB, [row128][k64] 128B rows
  __shared__ ushort_t Bsm[128 * 64];  // 16 KB
  __shared__ int rowid[128];

  const int t = threadIdx.x;
  const int lane = t & 63;
  const int w = t >> 6;
  if (t < 128) rowid[t] = sorted[start + ((t < rows) ? t : 0)];
  __syncthreads();

  // staging: call j covers LDS rows I*8..I*8+7 (I = j*4+w), 128B/row.
  // lane -> (row I*8+lr, chunk lc); A source pre-swizzled chunk lc^lr.
  const int lr = lane >> 3, lc = lane & 7;
  const int schunk = lc ^ lr;
  size_t aSrc[4];
  const ushort_t* bSrc[4];
  int ldOff[4];
  const ushort_t* bRegion = Wt + ((size_t)g * 16 * D_OUT + n_base) * 64;
#pragma unroll
  for (int j = 0; j < 4; ++j) {
    int I = j * 4 + w;
    aSrc[j] = (size_t)rowid[I * 8 + lr] * D_IN + schunk * 8;
    bSrc[j] = bRegion + I * 512 + lane * 8;
    ldOff[j] = I * 1024;  // bytes
  }

  const int fr = lane & 15;
  const int fk = lane >> 4;
  const int fk16 = fk * 16;
  const int xr = (fr & 7) << 4;
  const int wm = (w >> 1) * 64;
  const int wn = (w & 1) * 64;
  const char* aCh = (const char*)Asm + (wm + fr) * 128;
  const char* bCh = (const char*)Bsm + (wn + fr) * 128;

  f32x4 acc[4][4];
#pragma unroll
  for (int a = 0; a < 4; ++a)
#pragma unroll
    for (int b = 0; b < 4; ++b) acc[a][b] = (f32x4){0.f, 0.f, 0.f, 0.f};

  bf16x8 Af[2][4], Bf[2][4];

  for (int kt = 0; kt < NT_K; ++kt) {
    // stage tile kt (single buffer)
#pragma unroll
    for (int j = 0; j < 4; ++j)
      gload_lds16(Ab + aSrc[j] + (size_t)kt * 64, (char*)Asm + ldOff[j]);
#pragma unroll
    for (int j = 0; j < 4; ++j)
      gload_lds16(bSrc[j] + (size_t)kt * 262144, (char*)Bsm + ldOff[j]);
    __syncthreads();  // drains vmcnt; loads landed

#pragma unroll
    for (int ks = 0; ks < 2; ++ks) {
#pragma unroll
      for (int jm = 0; jm < 4; ++jm)
        Af[ks][jm] = *reinterpret_cast<const bf16x8*>(
            aCh + (jm * 16) * 128 + ((ks * 64 + fk16) ^ xr));
#pragma unroll
      for (int jn = 0; jn < 4; ++jn)
        Bf[ks][jn] = *reinterpret_cast<const bf16x8*>(
            bCh + (jn * 16) * 128 + ((ks * 64 + fk16) ^ xr));
    }
#pragma unroll
    for (int ks = 0; ks < 2; ++ks)
#pragma unroll
      for (int jm = 0; jm < 4; ++jm)
#pragma unroll
        for (int jn = 0; jn < 4; ++jn)
          acc[jm][jn] = __builtin_amdgcn_mfma_f32_16x16x32_bf16(
              Af[ks][jm], Bf[ks][jn], acc[jm][jn], 0, 0, 0);
    __syncthreads();  // reads done before next tile's writes
  }

  // epilogue: bias + masked scattered row stores
  const float* bp = bias + g * D_OUT + n_base + wn;
  float bv[4];
#pragma unroll
  for (int nb = 0; nb < 4; ++nb) bv[nb] = bp[nb * 16 + fr];
#pragma unroll
  for (int mb = 0; mb < 4; ++mb) {
#pragma unroll
    for (int r = 0; r < 4; ++r) {
      int m = wm + mb * 16 + fk * 4 + r;
      if (m < rows) {
        size_t ro = (size_t)rowid[m] * D_OUT + n_base + wn;
#pragma unroll
        for (int nb = 0; nb < 4; ++nb)
          out[ro + nb * 16 + fr] = acc[mb][nb][r] + bv[nb];
      }
    }
  }
}

// Fallback if workspace is too small: naive fp32 (correct, slow).
__global__ void k_naive(const float* __restrict__ A, const int* __restrict__ gi,
                        const float* __restrict__ W, const float* __restrict__ B,
                        float* __restrict__ out) {
  int row = blockIdx.x;
  int n = blockIdx.y * 256 + threadIdx.x;
  int g = gi[row];
  float s = B[(size_t)g * D_OUT + n];
  const float* wp = W + (size_t)g * D_IN * D_OUT + n;
  const float* a = A + (size_t)row * D_IN;
  for (int k = 0; k < D_IN; ++k) s += a[k] * wp[(size_t)k * D_OUT];
  out[(size_t)row * D_OUT + n] = s;
}

extern "C" void kernel_launch(void* const* d_in, const int* in_sizes, int n_in,
                              void* d_out, int out_size, void* d_ws, size_t ws_size,
                              hipStream_t stream) {
  const float* A = (const float*)d_in[0];
  const int* gi = (const int*)d_in[1];
  const float* W = (const float*)d_in[2];
  const float* B = (const float*)d_in[3];
  float* out = (float*)d_out;

  const size_t A_OFF = 65536;
  const size_t W_OFF = A_OFF + (size_t)N_ROWS * D_IN * 2;
  const size_t NEED = W_OFF + (size_t)NGROUPS * D_IN * D_OUT * 2;

  if (ws_size < NEED) {
    dim3 grid(N_ROWS, D_OUT / 256);
    k_naive<<<grid, dim3(256), 0, stream>>>(A, gi, W, B, out);
    return;
  }

  int* ctl = (int*)d_ws;
  int* sorted = ctl + CTL_SORTED;
  ushort_t* Ab = (ushort_t*)((char*)d_ws + A_OFF);
  ushort_t* Wt = (ushort_t*)((char*)d_ws + W_OFF);

  // fused prep: 1 sort block + 4096 convA blocks + 8192 transW blocks
  k_prep<<<1 + NCONV + 8192, 256, 0, stream>>>(A, gi, W, Ab, Wt, ctl, sorted);
  dim3 gg(32, MAX_MT);
  k_gemm<<<gg, 256, 0, stream>>>(Ab, Wt, ctl, sorted, B, out);
}